// Round 1
// baseline (131.164 us; speedup 1.0000x reference)
//
#include <hip/hip_runtime.h>

// GPTNeoXAttention qkv-split + RoPE + KV-cache concat for MI355X (gfx950).
// Shapes: B=2, S=2048, H=32, D=128, P=2048, ROT=32.
// Pure memory-bound streaming: ~335.5 MB read + ~335.5 MB write.

namespace {
constexpr int kB = 2;
constexpr int kS = 2048;
constexpr int kH = 32;
constexpr int kD = 128;
constexpr int kP = 2048;

constexpr unsigned QKV_VEC  = (unsigned)kB * kS * kH * 3 * kD / 4;  // 12582912 float4
constexpr unsigned PAST_VEC = (unsigned)kB * kH * kP * kD / 4;      //  4194304 float4
constexpr unsigned QN = (unsigned)kB * kH * kS * kD;                // 16777216 floats
constexpr unsigned KN = (unsigned)kB * kH * (kP + kS) * kD;         // 33554432 floats

// log2(10000)/16  (inv_freq[j] = 10000^(-j/16) = exp2(-j * this))
#define LOG2_10000_DIV16 0.83048202372184058696f
// 1/(2*pi)
#define INV_2PI 0.15915494309189535f
}  // namespace

// Copy past_key -> k_out[:, :, 0:P, :] and past_value -> v_out[:, :, 0:P, :].
// past flat f4 idx i: d4 = i&31, p = (i>>5)&2047, bh = i>>16.
// out f4 idx: (bh*4096 + p)*32 + d4   (out seq dim is P+S = 4096 rows).
__global__ __launch_bounds__(256) void copy_past_kernel(
    const float4* __restrict__ pk, const float4* __restrict__ pv,
    float4* __restrict__ ko, float4* __restrict__ vo) {
  unsigned i = blockIdx.x * 256u + threadIdx.x;
  unsigned d4 = i & 31u;
  unsigned p  = (i >> 5) & 2047u;
  unsigned bh = i >> 16;
  unsigned o = (bh * 4096u + p) * 32u + d4;
  ko[o] = pk[i];
  vo[o] = pv[i];
}

// One thread per float4 of qkv. qkv flat float idx = (((b*S+s)*H+h)*384 + c).
// c in [0,128): q; [128,256): k; [256,384): v.  RoPE on d = c%128 < 32 of q,k.
__global__ __launch_bounds__(256) void qkv_split_rope_kernel(
    const float4* __restrict__ qkv, float4* __restrict__ qo,
    float4* __restrict__ ko, float4* __restrict__ vo) {
  unsigned i = blockIdx.x * 256u + threadIdx.x;
  unsigned t    = i % 96u;       // float4 index within the 384-float (h) chunk
  unsigned rest = i / 96u;       // = (b*S+s)*H + h
  unsigned h = rest & 31u;
  unsigned s = (rest >> 5) & 2047u;
  unsigned b = rest >> 16;
  unsigned c = t * 4u;           // float offset within chunk
  unsigned sec = c >> 7;         // 0=q, 1=k, 2=v
  unsigned d = c & 127u;         // head-dim offset of this float4

  float4 x = qkv[i];
  float4 out = x;

  if (sec < 2u && d < 32u) {
    // RoPE. First half (d<16): out = x*cos - x[d+16]*sin
    //       Second half      : out = x*cos + x[d-16]*sin
    // Partner float4 is +-4 f4 away within the same head section.
    bool first = d < 16u;
    float4 part = qkv[first ? (i + 4u) : (i - 4u)];
    float pos = (float)(kP + (int)s);
    const float* xp = (const float*)&x;
    const float* pp = (const float*)&part;
    float* op = (float*)&out;
#pragma unroll
    for (int e = 0; e < 4; ++e) {
      float fi = (float)((d & 15u) + (unsigned)e);   // freq index 0..15
      float invf = __builtin_amdgcn_exp2f(fi * -LOG2_10000_DIV16);
      float rev = (pos * invf) * INV_2PI;            // angle in revolutions
      rev -= floorf(rev);                            // reduce to [0,1)
      float sn = __builtin_amdgcn_sinf(rev);         // v_sin_f32 (revolutions)
      float cs = __builtin_amdgcn_cosf(rev);
      op[e] = first ? (xp[e] * cs - pp[e] * sn)
                    : (xp[e] * cs + pp[e] * sn);
    }
  }

  unsigned bh = b * (unsigned)kH + h;
  unsigned d4 = d >> 2;
  if (sec == 0u) {
    unsigned o = (bh * (unsigned)kS + s) * 32u + d4;           // q: (B,H,S,D)
    qo[o] = out;
  } else if (sec == 1u) {
    unsigned o = (bh * 4096u + ((unsigned)kP + s)) * 32u + d4; // k rows P..P+S
    ko[o] = out;
  } else {
    unsigned o = (bh * 4096u + ((unsigned)kP + s)) * 32u + d4; // v rows P..P+S
    vo[o] = out;
  }
}

extern "C" void kernel_launch(void* const* d_in, const int* in_sizes, int n_in,
                              void* d_out, int out_size, void* d_ws, size_t ws_size,
                              hipStream_t stream) {
  const float4* qkv = (const float4*)d_in[0];
  const float4* pk  = (const float4*)d_in[1];
  const float4* pv  = (const float4*)d_in[2];
  float* out = (float*)d_out;
  float4* qo = (float4*)out;
  float4* ko = (float4*)(out + QN);
  float4* vo = (float4*)(out + QN + KN);

  copy_past_kernel<<<PAST_VEC / 256u, 256, 0, stream>>>(pk, pv, ko, vo);
  qkv_split_rope_kernel<<<QKV_VEC / 256u, 256, 0, stream>>>(qkv, qo, ko, vo);
}

// Round 3
// 104.164 us; speedup vs baseline: 1.2592x; 1.2592x over previous
//
#include <hip/hip_runtime.h>

// GPTNeoXAttention qkv-split + RoPE + KV-cache concat for MI355X (gfx950).
// Shapes: B=2, S=2048, H=32, D=128, P=2048, ROT=32.
// Memory-bound streaming: ~335.5 MB read + ~335.5 MB write. Roofline ~100-107us.
//
// R3: R2's plan with the compile fix — __builtin_nontemporal_* requires a
//     native clang vector type, not HIP_vector_type. Use ext_vector_type(4).

namespace {
typedef float f4 __attribute__((ext_vector_type(4)));  // native vec for nt builtins

constexpr int kB = 2;
constexpr int kS = 2048;
constexpr int kH = 32;
constexpr int kD = 128;
constexpr int kP = 2048;

constexpr unsigned QKV_VEC  = (unsigned)kB * kS * kH * 3 * kD / 4;  // 12582912 f4
constexpr unsigned PAST_VEC = (unsigned)kB * kH * kP * kD / 4;      //  4194304 f4
constexpr unsigned QN = (unsigned)kB * kH * kS * kD;                // 16777216 floats
constexpr unsigned KN = (unsigned)kB * kH * (kP + kS) * kD;         // 33554432 floats
constexpr unsigned TOTAL_VEC = 2u * PAST_VEC + QKV_VEC;             // 20971520 f4
// Region boundaries PAST_VEC (16384 blocks) and 2*PAST_VEC (32768 blocks) are
// block-aligned at 256 threads -> no intra-block region divergence.

// log2(10000)/16  (inv_freq[j] = 10000^(-j/16) = exp2(-j * this))
#define LOG2_10000_DIV16 0.83048202372184058696f
// 1/(2*pi)
#define INV_2PI 0.15915494309189535f
}  // namespace

__global__ __launch_bounds__(256) void fused_qkv_rope_concat_kernel(
    const f4* __restrict__ qkv, const f4* __restrict__ pk,
    const f4* __restrict__ pv, f4* __restrict__ qo,
    f4* __restrict__ ko, f4* __restrict__ vo) {
  unsigned i = blockIdx.x * 256u + threadIdx.x;

  if (i < 2u * PAST_VEC) {
    // ---- past_key / past_value -> rows [0, P) of k / v outputs ----
    bool is_k = i < PAST_VEC;
    unsigned j = is_k ? i : i - PAST_VEC;
    const f4* src = is_k ? pk : pv;
    f4* dst = is_k ? ko : vo;
    unsigned d4 = j & 31u;
    unsigned p  = (j >> 5) & 2047u;
    unsigned bh = j >> 16;
    f4 x = __builtin_nontemporal_load(&src[j]);
    __builtin_nontemporal_store(x, &dst[(bh * 4096u + p) * 32u + d4]);
    return;
  }

  // ---- qkv split + RoPE ----
  unsigned j = i - 2u * PAST_VEC;      // f4 index into qkv
  unsigned t    = j % 96u;             // f4 index within the 384-float chunk
  unsigned rest = j / 96u;             // = (b*S+s)*H + h
  unsigned h = rest & 31u;
  unsigned s = (rest >> 5) & 2047u;
  unsigned b = rest >> 16;
  unsigned c = t * 4u;                 // float offset within chunk
  unsigned sec = c >> 7;               // 0=q, 1=k, 2=v
  unsigned d = c & 127u;               // head-dim offset of this float4

  f4 x = qkv[j];
  f4 out = x;

  if (sec < 2u && d < 32u) {
    // RoPE: out[:16] = x*cos - x[+16]*sin ; out[16:32] = x*cos + x[-16]*sin
    bool first = d < 16u;
    f4 part = qkv[first ? (j + 4u) : (j - 4u)];   // cached (L1) reload
    float pos = (float)(kP + (int)s);
#pragma unroll
    for (int e = 0; e < 4; ++e) {
      float fi = (float)((d & 15u) + (unsigned)e);    // freq index 0..15
      float invf = __builtin_amdgcn_exp2f(fi * -LOG2_10000_DIV16);
      float rev = (pos * invf) * INV_2PI;             // angle in revolutions
      rev -= floorf(rev);                             // reduce to [0,1)
      float sn = __builtin_amdgcn_sinf(rev);          // v_sin_f32
      float cs = __builtin_amdgcn_cosf(rev);
      out[e] = first ? (x[e] * cs - part[e] * sn)
                     : (x[e] * cs + part[e] * sn);
    }
  }

  unsigned bh = b * (unsigned)kH + h;
  unsigned d4 = d >> 2;
  if (sec == 0u) {
    __builtin_nontemporal_store(out, &qo[(bh * (unsigned)kS + s) * 32u + d4]);
  } else if (sec == 1u) {
    __builtin_nontemporal_store(out, &ko[(bh * 4096u + (unsigned)kP + s) * 32u + d4]);
  } else {
    __builtin_nontemporal_store(out, &vo[(bh * 4096u + (unsigned)kP + s) * 32u + d4]);
  }
}

extern "C" void kernel_launch(void* const* d_in, const int* in_sizes, int n_in,
                              void* d_out, int out_size, void* d_ws, size_t ws_size,
                              hipStream_t stream) {
  const f4* qkv = (const f4*)d_in[0];
  const f4* pk  = (const f4*)d_in[1];
  const f4* pv  = (const f4*)d_in[2];
  float* out = (float*)d_out;
  f4* qo = (f4*)out;
  f4* ko = (f4*)(out + QN);
  f4* vo = (f4*)(out + QN + KN);

  fused_qkv_rope_concat_kernel<<<TOTAL_VEC / 256u, 256, 0, stream>>>(
      qkv, pk, pv, qo, ko, vo);
}